// Round 4
// baseline (271.673 us; speedup 1.0000x reference)
//
#include <hip/hip_runtime.h>

#define B_ 16
#define L_ 512
#define H_ 256
#define V_ 32000
#define HALF_ 128

typedef __attribute__((ext_vector_type(8))) short short8;
typedef __attribute__((ext_vector_type(4))) float floatx4;

__device__ __forceinline__ unsigned short f2bf(float x) {
  unsigned int u = __float_as_uint(x);
  unsigned int r = (u + 0x7FFFu + ((u >> 16) & 1u)) >> 16;
  return (unsigned short)r;
}

#define BL_(u) __uint_as_float((u) << 16)
#define BH_(u) __uint_as_float((u) & 0xffff0000u)

template <int CTRL>
__device__ __forceinline__ float dpp_xor_add(float x) {
  int y = __builtin_amdgcn_mov_dpp(__float_as_int(x), CTRL, 0xf, 0xf, true);
  return x + __int_as_float(y);
}

__device__ __forceinline__ float redu16(float p) {
  p = dpp_xor_add<0xB1>(p);   // xor1
  p = dpp_xor_add<0x4E>(p);   // xor2
  p = dpp_xor_add<0x141>(p);  // row_half_mirror (xor at quad granularity)
  p = dpp_xor_add<0x140>(p);  // row_mirror (xor at oct granularity)
  return p;
}

// ---------------- prep: embedding gather (fp32+bf16) + weight bf16 conversion ----------------
__global__ __launch_bounds__(256) void prep_kernel(const int* __restrict__ seq,
                                                   const float* __restrict__ embed,
                                                   float* __restrict__ h,
                                                   unsigned short* __restrict__ hbf,
                                                   const float* __restrict__ W1,
                                                   const float* __restrict__ W2,
                                                   const float* __restrict__ Ws,
                                                   const float* __restrict__ We,
                                                   unsigned short* __restrict__ W1b,
                                                   unsigned short* __restrict__ W2b,
                                                   unsigned short* __restrict__ Wcb) {
  int blk = blockIdx.x;
  int tid = threadIdx.x;
  if (blk < 2048) {
    int token = blk * 4 + (tid >> 6);
    int lane = tid & 63;
    int row = seq[token];
    float4 v = ((const float4*)(embed + (size_t)row * H_))[lane];
    ((float4*)(h + (size_t)token * H_))[lane] = v;
    ushort4 o;
    o.x = f2bf(v.x); o.y = f2bf(v.y); o.z = f2bf(v.z); o.w = f2bf(v.w);
    *(ushort4*)(hbf + (size_t)token * H_ + lane * 4) = o;
  } else {
    int i = (blk - 2048) * 256 + tid;  // 0..327679
    if (i < 131072) W1b[i] = f2bf(W1[i]);
    else if (i < 262144) W2b[i - 131072] = f2bf(W2[i - 131072]);
    else if (i < 294912) Wcb[i - 262144] = f2bf(Ws[i - 262144]);
    else Wcb[i - 262144] = f2bf(We[i - 294912]);
  }
}

// ---------------- bf16 MFMA GEMM: C[M,N(=128*gx)] = act(A @ B^T + bias + Res) ----------------
// MT x 128 tile, 4 waves (2x2), 16x16x32 MFMA. MT in {64,128}.
template <int MT, bool RELU, bool BIAS, bool RES, bool OUT_BF16>
__global__ __launch_bounds__(256) void gemm_mfma(const unsigned short* __restrict__ A,
                                                 const unsigned short* __restrict__ Bw,
                                                 const float* __restrict__ bias,
                                                 const float* __restrict__ Res,
                                                 float* __restrict__ Cf,
                                                 unsigned short* __restrict__ Cb,
                                                 int M, int N, int K) {
  constexpr int FI = MT / 32;  // M-frags per wave
  __shared__ unsigned short As[MT * 40];
  __shared__ unsigned short Bs[128 * 40];
  int tid = threadIdx.x;
  int wave = tid >> 6, lane = tid & 63;
  int wm = (wave >> 1) * (MT / 2), wn = (wave & 1) * 64;
  int quad = lane >> 4, l15 = lane & 15;
  int bm = blockIdx.y * MT, bn = blockIdx.x * 128;
  int sr = tid >> 2, sq = tid & 3;

  floatx4 zero = {0.f, 0.f, 0.f, 0.f};
  floatx4 acc[FI][4];
#pragma unroll
  for (int fi = 0; fi < FI; fi++)
#pragma unroll
    for (int fj = 0; fj < 4; fj++) acc[fi][fj] = zero;

  for (int k0 = 0; k0 < K; k0 += 32) {
    uint4 av0 = *(const uint4*)(A + (size_t)(bm + sr) * K + k0 + sq * 8);
    uint4 av1;
    if (MT == 128) av1 = *(const uint4*)(A + (size_t)(bm + 64 + sr) * K + k0 + sq * 8);
    uint4 bv0 = *(const uint4*)(Bw + (size_t)(bn + sr) * K + k0 + sq * 8);
    uint4 bv1 = *(const uint4*)(Bw + (size_t)(bn + 64 + sr) * K + k0 + sq * 8);
    __syncthreads();
    *(uint4*)(As + sr * 40 + sq * 8) = av0;
    if (MT == 128) *(uint4*)(As + (64 + sr) * 40 + sq * 8) = av1;
    *(uint4*)(Bs + sr * 40 + sq * 8) = bv0;
    *(uint4*)(Bs + (64 + sr) * 40 + sq * 8) = bv1;
    __syncthreads();
    short8 af[FI], bf[4];
#pragma unroll
    for (int f = 0; f < FI; f++) af[f] = *(const short8*)(As + (wm + f * 16 + l15) * 40 + quad * 8);
#pragma unroll
    for (int f = 0; f < 4; f++) bf[f] = *(const short8*)(Bs + (wn + f * 16 + l15) * 40 + quad * 8);
#pragma unroll
    for (int fi = 0; fi < FI; fi++)
#pragma unroll
      for (int fj = 0; fj < 4; fj++)
        acc[fi][fj] = __builtin_amdgcn_mfma_f32_16x16x32_bf16(af[fi], bf[fj], acc[fi][fj], 0, 0, 0);
  }

#pragma unroll
  for (int fi = 0; fi < FI; fi++) {
#pragma unroll
    for (int fj = 0; fj < 4; fj++) {
      int col = bn + wn + fj * 16 + l15;
      float bb = BIAS ? bias[col] : 0.f;
#pragma unroll
      for (int rg = 0; rg < 4; rg++) {
        int row = bm + wm + fi * 16 + quad * 4 + rg;
        float v = acc[fi][fj][rg] + bb;
        if (RES) v += Res[(size_t)row * N + col];
        if (RELU) v = fmaxf(v, 0.f);
        if (OUT_BF16) Cb[(size_t)row * N + col] = f2bf(v);
        else Cf[(size_t)row * N + col] = v;
      }
    }
  }
}

// ---------------- LayerNorm over H=256, one wave per row; bf16 output ----------------
__global__ void ln_kernel(const float* __restrict__ x, const float* __restrict__ gamma,
                          const float* __restrict__ beta, unsigned short* __restrict__ yb) {
  int row = blockIdx.x;
  int lane = threadIdx.x;  // 64
  float4 v = ((const float4*)(x + (size_t)row * H_))[lane];
  float s = v.x + v.y + v.z + v.w;
  float sq = v.x * v.x + v.y * v.y + v.z * v.z + v.w * v.w;
#pragma unroll
  for (int off = 32; off >= 1; off >>= 1) {
    s += __shfl_xor(s, off);
    sq += __shfl_xor(sq, off);
  }
  float mu = s * (1.f / H_);
  float var = sq * (1.f / H_) - mu * mu;
  float inv = rsqrtf(var + 1e-5f);
  float4 g = ((const float4*)gamma)[lane];
  float4 b = ((const float4*)beta)[lane];
  ushort4 o;
  o.x = f2bf((v.x - mu) * inv * g.x + b.x);
  o.y = f2bf((v.y - mu) * inv * g.y + b.y);
  o.z = f2bf((v.z - mu) * inv * g.z + b.z);
  o.w = f2bf((v.w - mu) * inv * g.w + b.w);
  *(ushort4*)(yb + (size_t)row * H_ + lane * 4) = o;
}

// ---------------- normalize keys -> bf16 khat[idxm][t][128] ----------------
__global__ __launch_bounds__(256) void normalize_kernel(const float* __restrict__ kcat,
                                                        unsigned short* __restrict__ khat) {
  int e = blockIdx.x * 4 + (threadIdx.x >> 6);  // e = idxm*512 + t
  int lane = threadIdx.x & 63;
  int idxm = e >> 9, t = e & 511;
  int b = idxm >> 1, mat = idxm & 1;
  const float* kp = kcat + ((size_t)b * L_ + t) * 256 + mat * 128;
  float2 v = ((const float2*)kp)[lane];
  float s = v.x * v.x + v.y * v.y;
#pragma unroll
  for (int off = 32; off >= 1; off >>= 1) s += __shfl_xor(s, off);
  float inv = 1.f / fmaxf(sqrtf(s), 1e-12f);
  ushort2 o;
  o.x = f2bf(v.x * inv);
  o.y = f2bf(v.y * inv);
  *(ushort2*)(khat + (size_t)e * HALF_ + lane * 2) = o;
}

// ---------------- Gram dots within chunks of 4: gram[idxm][ch][{01,02,03,12,13,23}] ----------------
__global__ __launch_bounds__(256) void gram_kernel(const unsigned short* __restrict__ khat,
                                                   float* __restrict__ gram) {
  int e = blockIdx.x * 4 + (threadIdx.x >> 6);  // 0..4095 = idxm*128 + ch
  int lane = threadIdx.x & 63;
  int idxm = e >> 7, ch = e & 127;
  const unsigned short* kp = khat + ((size_t)idxm * L_ + ch * 4) * HALF_ + lane * 2;
  float2 a[4];
#pragma unroll
  for (int i = 0; i < 4; i++) {
    unsigned int w = *(const unsigned int*)(kp + i * HALF_);
    a[i].x = BL_(w);
    a[i].y = BH_(w);
  }
  float s01 = a[0].x * a[1].x + a[0].y * a[1].y;
  float s02 = a[0].x * a[2].x + a[0].y * a[2].y;
  float s03 = a[0].x * a[3].x + a[0].y * a[3].y;
  float s12 = a[1].x * a[2].x + a[1].y * a[2].y;
  float s13 = a[1].x * a[3].x + a[1].y * a[3].y;
  float s23 = a[2].x * a[3].x + a[2].y * a[3].y;
#pragma unroll
  for (int off = 32; off >= 1; off >>= 1) {
    s01 += __shfl_xor(s01, off);
    s02 += __shfl_xor(s02, off);
    s03 += __shfl_xor(s03, off);
    s12 += __shfl_xor(s12, off);
    s13 += __shfl_xor(s13, off);
    s23 += __shfl_xor(s23, off);
  }
  if (lane == 0) {
    float4 g0 = {s01, s02, s03, s12};
    float2 g1 = {s13, s23};
    *(float4*)(gram + (size_t)e * 8) = g0;
    *(float2*)(gram + (size_t)e * 8 + 4) = g1;
  }
}

// ---------------- chunked (WY) delta-rule scan ----------------
#define UNPK(P, K)                                                         \
  float K##0 = BL_(P.x), K##1 = BH_(P.x), K##2 = BL_(P.y), K##3 = BH_(P.y), \
        K##4 = BL_(P.z), K##5 = BH_(P.z), K##6 = BL_(P.w), K##7 = BH_(P.w);

#define DOT8(K, OUT)                                                     \
  float OUT;                                                             \
  {                                                                      \
    float a_ = m[0] * K##0 + m[1] * K##1, b_ = m[2] * K##2 + m[3] * K##3, \
          c_ = m[4] * K##4 + m[5] * K##5, d_ = m[6] * K##6 + m[7] * K##7; \
    OUT = (a_ + b_) + (c_ + d_);                                         \
  }

#define SCAN_STEP(PK, PR)                                                \
  do {                                                                   \
    UNPK(PK, kz)                                                         \
    DOT8(kz, p_)                                                         \
    p_ = redu16(p_);                                                     \
    float sS = PR - p_;                                                  \
    m[0] += sS * kz0; m[1] += sS * kz1; m[2] += sS * kz2; m[3] += sS * kz3; \
    m[4] += sS * kz4; m[5] += sS * kz5; m[6] += sS * kz6; m[7] += sS * kz7; \
  } while (0)

__global__ __launch_bounds__(256) void scan_kernel(const float* __restrict__ kcat,
                                                   const unsigned short* __restrict__ khat,
                                                   const float* __restrict__ gram,
                                                   float* __restrict__ c) {
  int bid = blockIdx.x;
  int idxm = bid & 31;  // XCD swizzle: 8 blocks of one idxm share an XCD L2
  int rg = bid >> 5;
  int b = idxm >> 1, mat = idxm & 1;
  const unsigned short* kh = khat + (size_t)idxm * L_ * HALF_;
  const float* kbase = kcat + (size_t)b * L_ * 256 + mat * HALF_;
  const float* gp = gram + (size_t)idxm * 128 * 8;

  int tid = threadIdx.x;
  int seg = tid & 15;   // 16 lanes per row
  int rl = tid >> 4;    // 0..15
  int r = rg * 16 + rl;
  int c0 = seg * 8;
  const float* krow = kbase + r;

  float m[8];
#pragma unroll
  for (int g = 0; g < 8; g++) m[g] = 0.f;

  // chunk-0 preload
  uint4 pk0 = *(const uint4*)(kh + 0 * HALF_ + c0);
  uint4 pk1 = *(const uint4*)(kh + 1 * HALF_ + c0);
  uint4 pk2 = *(const uint4*)(kh + 2 * HALF_ + c0);
  uint4 pk3 = *(const uint4*)(kh + 3 * HALF_ + c0);
  float pr0 = krow[0], pr1 = krow[256], pr2 = krow[512], pr3 = krow[768];
  float4 g03 = *(const float4*)(gp);       // G01,G02,G03,G12
  float2 g45 = *(const float2*)(gp + 4);   // G13,G23

  for (int ch = 0; ch < 127; ch++) {
    // prefetch chunk ch+1
    const unsigned short* kn = kh + (size_t)(ch + 1) * 4 * HALF_ + c0;
    uint4 n0 = *(const uint4*)(kn);
    uint4 n1 = *(const uint4*)(kn + HALF_);
    uint4 n2 = *(const uint4*)(kn + 2 * HALF_);
    uint4 n3 = *(const uint4*)(kn + 3 * HALF_);
    const float* rn = krow + (size_t)(ch + 1) * 4 * 256;
    float nr0 = rn[0], nr1 = rn[256], nr2 = rn[512], nr3 = rn[768];
    float4 ng03 = *(const float4*)(gp + (size_t)(ch + 1) * 8);
    float2 ng45 = *(const float2*)(gp + (size_t)(ch + 1) * 8 + 4);

    // WY chunk of 4: all dots vs current M, then corrected deltas, then rank-4 update
    {
      UNPK(pk0, ka) UNPK(pk1, kb) UNPK(pk2, kc) UNPK(pk3, kd)
      DOT8(ka, p0) DOT8(kb, p1) DOT8(kc, p2) DOT8(kd, p3)
      p0 = redu16(p0);
      p1 = redu16(p1);
      p2 = redu16(p2);
      p3 = redu16(p3);
      float d0 = pr0 - p0;
      float d1 = pr1 - p1 - g03.x * d0;
      float d2 = pr2 - p2 - g03.y * d0 - g03.w * d1;
      float d3 = pr3 - p3 - g03.z * d0 - g45.x * d1 - g45.y * d2;
      m[0] += d0 * ka0 + d1 * kb0 + d2 * kc0 + d3 * kd0;
      m[1] += d0 * ka1 + d1 * kb1 + d2 * kc1 + d3 * kd1;
      m[2] += d0 * ka2 + d1 * kb2 + d2 * kc2 + d3 * kd2;
      m[3] += d0 * ka3 + d1 * kb3 + d2 * kc3 + d3 * kd3;
      m[4] += d0 * ka4 + d1 * kb4 + d2 * kc4 + d3 * kd4;
      m[5] += d0 * ka5 + d1 * kb5 + d2 * kc5 + d3 * kd5;
      m[6] += d0 * ka6 + d1 * kb6 + d2 * kc6 + d3 * kd6;
      m[7] += d0 * ka7 + d1 * kb7 + d2 * kc7 + d3 * kd7;
    }

    pk0 = n0; pk1 = n1; pk2 = n2; pk3 = n3;
    pr0 = nr0; pr1 = nr1; pr2 = nr2; pr3 = nr3;
    g03 = ng03; g45 = ng45;
  }

  // tail: steps 508,509,510 (chunk-127 data already in regs)
  SCAN_STEP(pk0, pr0);
  SCAN_STEP(pk1, pr1);
  SCAN_STEP(pk2, pr2);

  // final read with raw fp32 last-token key (t=511)
  float4 qa = *(const float4*)(kbase + (size_t)511 * 256 + c0);
  float4 qb = *(const float4*)(kbase + (size_t)511 * 256 + c0 + 4);
  float pa = m[0] * qa.x + m[1] * qa.y, pb2 = m[2] * qa.z + m[3] * qa.w;
  float pc = m[4] * qb.x + m[5] * qb.y, pd = m[6] * qb.z + m[7] * qb.w;
  float p = redu16((pa + pb2) + (pc + pd));
  if (seg == 0) c[(size_t)b * H_ + mat * HALF_ + r] = p;
}

// ---------------- r = c @ W_rp^T + b_rp ----------------
__global__ void rp_kernel(const float* __restrict__ c, const float* __restrict__ Wrp,
                          const float* __restrict__ brp, float* __restrict__ r) {
  int b = blockIdx.x;
  int n = threadIdx.x;  // 256
  __shared__ float cs[H_];
  cs[n] = c[(size_t)b * H_ + n];
  __syncthreads();
  const float4* w4 = (const float4*)(Wrp + (size_t)n * H_);
  const float4* c4 = (const float4*)cs;
  float acc = 0.f;
#pragma unroll 8
  for (int k = 0; k < H_ / 4; k++) {
    float4 w = w4[k], cc = c4[k];
    acc += w.x * cc.x + w.y * cc.y + w.z * cc.z + w.w * cc.w;
  }
  r[(size_t)b * H_ + n] = acc + brp[n];
}

// ---------------- out = r @ W_out^T + b_out, coalesced: 64 vocab rows/block ----------------
__global__ __launch_bounds__(256) void out_kernel(const float* __restrict__ r,
                                                  const float* __restrict__ Wout,
                                                  const float* __restrict__ bout,
                                                  float* __restrict__ out) {
  __shared__ float rs[16 * 272];   // swizzled: col c at c + 4*(c>>6)
  __shared__ float obuf[16 * 68];
  int tid = threadIdx.x;
#pragma unroll
  for (int q = 0; q < 16; q++) {
    int idx = q * 256 + tid;
    int bb = idx >> 8, cc = idx & 255;
    rs[bb * 272 + cc + 4 * (cc >> 6)] = r[idx];
  }
  __syncthreads();
  int row = tid >> 2, part = tid & 3;
  int v = blockIdx.x * 64 + row;
  const float4* w4 = (const float4*)(Wout + (size_t)v * H_ + part * 64);
  float acc[16];
#pragma unroll
  for (int bb = 0; bb < 16; bb++) acc[bb] = 0.f;
#pragma unroll 4
  for (int j = 0; j < 16; j++) {
    float4 w = w4[j];
#pragma unroll
    for (int bb = 0; bb < 16; bb++) {
      float4 rv = *(const float4*)&rs[bb * 272 + part * 68 + j * 4];
      acc[bb] += w.x * rv.x + w.y * rv.y + w.z * rv.z + w.w * rv.w;
    }
  }
  float bo = bout[v];
#pragma unroll
  for (int bb = 0; bb < 16; bb++) {
    acc[bb] = dpp_xor_add<0xB1>(acc[bb]);
    acc[bb] = dpp_xor_add<0x4E>(acc[bb]);
  }
#pragma unroll
  for (int q = 0; q < 4; q++) {
    int bb = part * 4 + q;
    obuf[bb * 68 + row] = acc[bb] + bo;
  }
  __syncthreads();
#pragma unroll
  for (int q = 0; q < 4; q++) {
    int idx = q * 256 + tid;
    int bb = idx >> 6, vl = idx & 63;
    out[(size_t)bb * V_ + blockIdx.x * 64 + vl] = obuf[bb * 68 + vl];
  }
}

extern "C" void kernel_launch(void* const* d_in, const int* in_sizes, int n_in,
                              void* d_out, int out_size, void* d_ws, size_t ws_size,
                              hipStream_t stream) {
  const int* seq = (const int*)d_in[0];
  const float* embed = (const float*)d_in[1];
  const float* W1 = (const float*)d_in[2];
  const float* b1 = (const float*)d_in[3];
  const float* W2 = (const float*)d_in[4];
  const float* b2 = (const float*)d_in[5];
  const float* gamma = (const float*)d_in[6];
  const float* beta = (const float*)d_in[7];
  const float* Wsem = (const float*)d_in[8];
  const float* Wepi = (const float*)d_in[9];
  const float* Wrp = (const float*)d_in[10];
  const float* brp = (const float*)d_in[11];
  const float* Wout = (const float*)d_in[12];
  const float* bout = (const float*)d_in[13];
  float* out = (float*)d_out;

  float* ws = (float*)d_ws;
  float* h = ws;                                           // [8192,256] fp32; x in-place
  float* x = h;
  float* kcat = ws + 2097152;                              // [8192,256] fp32
  unsigned short* a1b = (unsigned short*)kcat;             // [8192,512] bf16 (dead before kcat)
  unsigned short* hbf = (unsigned short*)(ws + 4194304);   // [8192,256] bf16
  float* gram = ws + 4718592;                              // 32*128*8 floats (hbf region unused tail)
  unsigned short* hnb = (unsigned short*)(ws + 5242880);   // [8192,256] bf16
  unsigned short* khat = (unsigned short*)(ws + 6291456);  // [32,512,128] bf16
  unsigned short* W1b = (unsigned short*)(ws + 7340032);
  unsigned short* W2b = (unsigned short*)(ws + 7405568);
  unsigned short* Wcb = (unsigned short*)(ws + 7471104);
  float* c = ws + 7503872;
  float* r = ws + 7508000;

  // 1. gather + weight conversion (fused)
  prep_kernel<<<3328, 256, 0, stream>>>(seq, embed, h, hbf, W1, W2, Wsem, Wepi, W1b, W2b, Wcb);
  // 2. a1 = relu(h @ W1^T + b1) -> bf16  [8192,512]
  gemm_mfma<128, true, true, false, true><<<dim3(4, 64), 256, 0, stream>>>(
      hbf, W1b, b1, nullptr, nullptr, a1b, 8192, 512, 256);
  // 3. x = a1 @ W2^T + b2 + h -> fp32 (in-place over h)  [8192,256]
  gemm_mfma<64, false, true, true, false><<<dim3(2, 128), 256, 0, stream>>>(
      a1b, W2b, b2, h, x, nullptr, 8192, 256, 512);
  // 4. hn = LayerNorm(x) -> bf16
  ln_kernel<<<8192, 64, 0, stream>>>(x, gamma, beta, hnb);
  // 5. kcat = hn @ [Wsem;Wepi]^T -> fp32  [8192,256]
  gemm_mfma<64, false, false, false, false><<<dim3(2, 128), 256, 0, stream>>>(
      hnb, Wcb, nullptr, nullptr, kcat, nullptr, 8192, 256, 256);
  // 6. khat = normalize(k) -> bf16
  normalize_kernel<<<4096, 256, 0, stream>>>(kcat, khat);
  // 7. Gram dots per chunk of 4
  gram_kernel<<<1024, 256, 0, stream>>>(khat, gram);
  // 8. chunked delta-rule scan -> c [16,256]
  scan_kernel<<<256, 256, 0, stream>>>(kcat, khat, gram, c);
  // 9. r = c @ Wrp^T + brp
  rp_kernel<<<16, 256, 0, stream>>>(c, Wrp, brp, r);
  // 10. out = r @ Wout^T + bout  [16,32000]
  out_kernel<<<500, 256, 0, stream>>>(r, Wout, bout, out);
}

// Round 5
// 246.901 us; speedup vs baseline: 1.1003x; 1.1003x over previous
//
#include <hip/hip_runtime.h>

#define B_ 16
#define L_ 512
#define H_ 256
#define V_ 32000
#define HALF_ 128

typedef __attribute__((ext_vector_type(8))) short short8;
typedef __attribute__((ext_vector_type(4))) float floatx4;

__device__ __forceinline__ unsigned short f2bf(float x) {
  unsigned int u = __float_as_uint(x);
  unsigned int r = (u + 0x7FFFu + ((u >> 16) & 1u)) >> 16;
  return (unsigned short)r;
}

template <int CTRL>
__device__ __forceinline__ float dpp_xor_add(float x) {
  int y = __builtin_amdgcn_mov_dpp(__float_as_int(x), CTRL, 0xf, 0xf, true);
  return x + __int_as_float(y);
}

// butterfly sum over aligned 16-lane groups; ALL lanes get the result
__device__ __forceinline__ float redu16(float p) {
  p = dpp_xor_add<0xB1>(p);   // xor1 (quad_perm 1,0,3,2)
  p = dpp_xor_add<0x4E>(p);   // xor2 (quad_perm 2,3,0,1)
  p = dpp_xor_add<0x141>(p);  // row_half_mirror
  p = dpp_xor_add<0x140>(p);  // row_mirror
  return p;
}

// ---------------- weight -> bf16 conversion ----------------
__global__ __launch_bounds__(256) void wconv_kernel(const float* __restrict__ W1,
                                                    const float* __restrict__ W2,
                                                    const float* __restrict__ Ws,
                                                    const float* __restrict__ We,
                                                    unsigned short* __restrict__ W1b,
                                                    unsigned short* __restrict__ W2b,
                                                    unsigned short* __restrict__ Wcb) {
  int i = blockIdx.x * 256 + threadIdx.x;  // 0..327679
  if (i < 131072) W1b[i] = f2bf(W1[i]);
  else if (i < 262144) W2b[i - 131072] = f2bf(W2[i - 131072]);
  else if (i < 294912) Wcb[i - 262144] = f2bf(Ws[i - 262144]);
  else Wcb[i - 262144] = f2bf(We[i - 294912]);
}

__device__ __forceinline__ uint4 load8cvt(const float* p) {
  float4 a = ((const float4*)p)[0];
  float4 b = ((const float4*)p)[1];
  uint4 r;
  r.x = (unsigned)f2bf(a.x) | ((unsigned)f2bf(a.y) << 16);
  r.y = (unsigned)f2bf(a.z) | ((unsigned)f2bf(a.w) << 16);
  r.z = (unsigned)f2bf(b.x) | ((unsigned)f2bf(b.y) << 16);
  r.w = (unsigned)f2bf(b.z) | ((unsigned)f2bf(b.w) << 16);
  return r;
}

// ---------------- GEMM1: a1 = relu(embed[seq] @ W1^T + b1) -> bf16, gather fused ----------------
// 128x128 tile, 4 waves (2x2), K=256.
__global__ __launch_bounds__(256) void gemm1_kernel(const int* __restrict__ seq,
                                                    const float* __restrict__ embed,
                                                    const unsigned short* __restrict__ W1b,
                                                    const float* __restrict__ b1,
                                                    unsigned short* __restrict__ a1b) {
  __shared__ unsigned short As[128 * 40];
  __shared__ unsigned short Bs[128 * 40];
  int tid = threadIdx.x;
  int wave = tid >> 6, lane = tid & 63;
  int wm = (wave >> 1) * 64, wn = (wave & 1) * 64;
  int quad = lane >> 4, l15 = lane & 15;
  int bm = blockIdx.y * 128, bn = blockIdx.x * 128;
  int sr = tid >> 2, sq = tid & 3;

  int tok0 = seq[bm + sr];
  int tok1 = seq[bm + 64 + sr];

  floatx4 zero = {0.f, 0.f, 0.f, 0.f};
  floatx4 acc[2][4];
#pragma unroll
  for (int fi = 0; fi < 2; fi++)
#pragma unroll
    for (int fj = 0; fj < 4; fj++) acc[fi][fj] = zero;
  floatx4 acc2[2][4];
#pragma unroll
  for (int fi = 0; fi < 2; fi++)
#pragma unroll
    for (int fj = 0; fj < 4; fj++) acc2[fi][fj] = zero;

  for (int k0 = 0; k0 < 256; k0 += 32) {
    uint4 av0 = load8cvt(embed + (size_t)tok0 * H_ + k0 + sq * 8);
    uint4 av1 = load8cvt(embed + (size_t)tok1 * H_ + k0 + sq * 8);
    uint4 bv0 = *(const uint4*)(W1b + (size_t)(bn + sr) * 256 + k0 + sq * 8);
    uint4 bv1 = *(const uint4*)(W1b + (size_t)(bn + 64 + sr) * 256 + k0 + sq * 8);
    __syncthreads();
    *(uint4*)(As + sr * 40 + sq * 8) = av0;
    *(uint4*)(As + (64 + sr) * 40 + sq * 8) = av1;
    *(uint4*)(Bs + sr * 40 + sq * 8) = bv0;
    *(uint4*)(Bs + (64 + sr) * 40 + sq * 8) = bv1;
    __syncthreads();
    short8 af[4], bf[4];
#pragma unroll
    for (int f = 0; f < 4; f++) {
      af[f] = *(const short8*)(As + (wm + f * 16 + l15) * 40 + quad * 8);
      bf[f] = *(const short8*)(Bs + (wn + f * 16 + l15) * 40 + quad * 8);
    }
#pragma unroll
    for (int fi = 0; fi < 2; fi++)
#pragma unroll
      for (int fj = 0; fj < 4; fj++) {
        acc[fi][fj] = __builtin_amdgcn_mfma_f32_16x16x32_bf16(af[fi], bf[fj], acc[fi][fj], 0, 0, 0);
        acc2[fi][fj] = __builtin_amdgcn_mfma_f32_16x16x32_bf16(af[fi + 2], bf[fj], acc2[fi][fj], 0, 0, 0);
      }
  }

#pragma unroll
  for (int fi = 0; fi < 4; fi++) {
#pragma unroll
    for (int fj = 0; fj < 4; fj++) {
      int col = bn + wn + fj * 16 + l15;
      float bb = b1[col];
      floatx4 a = (fi < 2) ? acc[fi][fj] : acc2[fi - 2][fj];
#pragma unroll
      for (int rg = 0; rg < 4; rg++) {
        int row = bm + wm + fi * 16 + quad * 4 + rg;
        float v = fmaxf(a[rg] + bb, 0.f);
        a1b[(size_t)row * 512 + col] = f2bf(v);
      }
    }
  }
}

// ---------------- GEMM2+LN: hn = LN(a1 @ W2^T + b2 + embed[seq]) -> bf16 ----------------
// 32x256 tile (full N), 4 waves: wave_m in {0,1} x 16 rows, wave_n in {0,1} x 128 cols. K=512.
__global__ __launch_bounds__(256) void mlp2_kernel(const unsigned short* __restrict__ a1b,
                                                   const unsigned short* __restrict__ W2b,
                                                   const float* __restrict__ b2,
                                                   const int* __restrict__ seq,
                                                   const float* __restrict__ embed,
                                                   const float* __restrict__ gamma,
                                                   const float* __restrict__ beta,
                                                   unsigned short* __restrict__ hnb) {
  __shared__ unsigned short As[32 * 40];
  __shared__ unsigned short Bs[256 * 40];
  __shared__ float stats[2][2][32];  // [wn_half][sum/ssq][rowlocal]
  int tid = threadIdx.x;
  int wave = tid >> 6, lane = tid & 63;
  int wm = (wave >> 1) * 16, wnh = wave & 1, wn = wnh * 128;
  int quad = lane >> 4, l15 = lane & 15;
  int bm = blockIdx.x * 32;

  floatx4 zero = {0.f, 0.f, 0.f, 0.f};
  floatx4 acc[8];
#pragma unroll
  for (int fj = 0; fj < 8; fj++) acc[fj] = zero;

  for (int k0 = 0; k0 < 512; k0 += 32) {
    uint4 av;
    if (tid < 128) {
      int sr = tid >> 2, sq = tid & 3;
      av = *(const uint4*)(a1b + (size_t)(bm + sr) * 512 + k0 + sq * 8);
    }
    uint4 bv[4];
#pragma unroll
    for (int q = 0; q < 4; q++) {
      int unit = q * 256 + tid;
      int row = unit >> 2, sq2 = unit & 3;
      bv[q] = *(const uint4*)(W2b + (size_t)row * 512 + k0 + sq2 * 8);
    }
    __syncthreads();
    if (tid < 128) {
      int sr = tid >> 2, sq = tid & 3;
      *(uint4*)(As + sr * 40 + sq * 8) = av;
    }
#pragma unroll
    for (int q = 0; q < 4; q++) {
      int unit = q * 256 + tid;
      int row = unit >> 2, sq2 = unit & 3;
      *(uint4*)(Bs + row * 40 + sq2 * 8) = bv[q];
    }
    __syncthreads();
    short8 af = *(const short8*)(As + (wm + l15) * 40 + quad * 8);
    short8 bf[8];
#pragma unroll
    for (int fj = 0; fj < 8; fj++)
      bf[fj] = *(const short8*)(Bs + (wn + fj * 16 + l15) * 40 + quad * 8);
#pragma unroll
    for (int fj = 0; fj < 8; fj++)
      acc[fj] = __builtin_amdgcn_mfma_f32_16x16x32_bf16(af, bf[fj], acc[fj], 0, 0, 0);
  }

  // epilogue: x = acc + b2 + embed[seq[row]]; LN over 256 cols
  int seqv[4];
#pragma unroll
  for (int rg = 0; rg < 4; rg++) seqv[rg] = seq[bm + wm + quad * 4 + rg];
  float v[8][4];
#pragma unroll
  for (int fj = 0; fj < 8; fj++) {
    int col = wn + fj * 16 + l15;
    float bb = b2[col];
#pragma unroll
    for (int rg = 0; rg < 4; rg++)
      v[fj][rg] = acc[fj][rg] + bb + embed[(size_t)seqv[rg] * H_ + col];
  }
  float s_[4], q_[4];
#pragma unroll
  for (int rg = 0; rg < 4; rg++) {
    float s = 0.f, q = 0.f;
#pragma unroll
    for (int fj = 0; fj < 8; fj++) {
      s += v[fj][rg];
      q += v[fj][rg] * v[fj][rg];
    }
    s_[rg] = redu16(s);
    q_[rg] = redu16(q);
  }
  if (l15 == 0) {
#pragma unroll
    for (int rg = 0; rg < 4; rg++) {
      int rlocal = wm + quad * 4 + rg;
      stats[wnh][0][rlocal] = s_[rg];
      stats[wnh][1][rlocal] = q_[rg];
    }
  }
  __syncthreads();
  float mu[4], inv[4];
#pragma unroll
  for (int rg = 0; rg < 4; rg++) {
    int rlocal = wm + quad * 4 + rg;
    float sum = stats[0][0][rlocal] + stats[1][0][rlocal];
    float ssq = stats[0][1][rlocal] + stats[1][1][rlocal];
    mu[rg] = sum * (1.f / H_);
    float var = ssq * (1.f / H_) - mu[rg] * mu[rg];
    inv[rg] = rsqrtf(var + 1e-5f);
  }
#pragma unroll
  for (int fj = 0; fj < 8; fj++) {
    int col = wn + fj * 16 + l15;
    float g = gamma[col], be = beta[col];
#pragma unroll
    for (int rg = 0; rg < 4; rg++) {
      int row = bm + wm + quad * 4 + rg;
      float y = (v[fj][rg] - mu[rg]) * inv[rg] * g + be;
      hnb[(size_t)row * H_ + col] = f2bf(y);
    }
  }
}

// ---------------- KPROJ: k = hn @ [Wsem;Wepi]^T; write khat fp32 + raw kT (transposed) ----------------
// 32x256 tile; each wave owns a full 128-dim half -> pure-DPP norms.
__global__ __launch_bounds__(256) void kproj_kernel(const unsigned short* __restrict__ hnb,
                                                    const unsigned short* __restrict__ Wcb,
                                                    float* __restrict__ khat,
                                                    float* __restrict__ kT) {
  __shared__ unsigned short As[32 * 40];
  __shared__ unsigned short Bs[256 * 40];
  int tid = threadIdx.x;
  int wave = tid >> 6, lane = tid & 63;
  int wm = (wave >> 1) * 16, wnh = wave & 1, wn = wnh * 128;
  int quad = lane >> 4, l15 = lane & 15;
  int bm = blockIdx.x * 32;

  floatx4 zero = {0.f, 0.f, 0.f, 0.f};
  floatx4 acc[8];
#pragma unroll
  for (int fj = 0; fj < 8; fj++) acc[fj] = zero;

  for (int k0 = 0; k0 < 256; k0 += 32) {
    uint4 av;
    if (tid < 128) {
      int sr = tid >> 2, sq = tid & 3;
      av = *(const uint4*)(hnb + (size_t)(bm + sr) * H_ + k0 + sq * 8);
    }
    uint4 bv[4];
#pragma unroll
    for (int q = 0; q < 4; q++) {
      int unit = q * 256 + tid;
      int row = unit >> 2, sq2 = unit & 3;
      bv[q] = *(const uint4*)(Wcb + (size_t)row * H_ + k0 + sq2 * 8);
    }
    __syncthreads();
    if (tid < 128) {
      int sr = tid >> 2, sq = tid & 3;
      *(uint4*)(As + sr * 40 + sq * 8) = av;
    }
#pragma unroll
    for (int q = 0; q < 4; q++) {
      int unit = q * 256 + tid;
      int row = unit >> 2, sq2 = unit & 3;
      *(uint4*)(Bs + row * 40 + sq2 * 8) = bv[q];
    }
    __syncthreads();
    short8 af = *(const short8*)(As + (wm + l15) * 40 + quad * 8);
    short8 bf[8];
#pragma unroll
    for (int fj = 0; fj < 8; fj++)
      bf[fj] = *(const short8*)(Bs + (wn + fj * 16 + l15) * 40 + quad * 8);
#pragma unroll
    for (int fj = 0; fj < 8; fj++)
      acc[fj] = __builtin_amdgcn_mfma_f32_16x16x32_bf16(af, bf[fj], acc[fj], 0, 0, 0);
  }

  // epilogue: per-row, per-half L2 norm (this wave holds the entire 128-dim half)
  int b = bm >> 9;
  int idxm = b * 2 + wnh;
  int tloc0 = (bm & 511) + wm + quad * 4;
  float inv[4];
#pragma unroll
  for (int rg = 0; rg < 4; rg++) {
    float ssq = 0.f;
#pragma unroll
    for (int fj = 0; fj < 8; fj++) ssq += acc[fj][rg] * acc[fj][rg];
    ssq = redu16(ssq);
    inv[rg] = 1.f / fmaxf(sqrtf(ssq), 1e-12f);
  }
#pragma unroll
  for (int fj = 0; fj < 8; fj++) {
    int ch = fj * 16 + l15;  // 0..127 within half
    // khat[idxm][t][c] normalized fp32
#pragma unroll
    for (int rg = 0; rg < 4; rg++)
      khat[((size_t)idxm * L_ + tloc0 + rg) * HALF_ + ch] = acc[fj][rg] * inv[rg];
    // kT[idxm][c][t] raw fp32, t-contiguous float4
    float4 raw = {acc[fj][0], acc[fj][1], acc[fj][2], acc[fj][3]};
    *(float4*)(kT + (size_t)idxm * (HALF_ * L_) + (size_t)ch * L_ + tloc0) = raw;
  }
}

// ---------------- row-parallel delta-rule scan: fp32 khat, 8-step pipeline ----------------
#define STEP8(KP, PR)                                                      \
  do {                                                                     \
    float t0_ = m[0] * KP[0] + m[1] * KP[1];                               \
    float t1_ = m[2] * KP[2] + m[3] * KP[3];                               \
    float t2_ = m[4] * KP[4] + m[5] * KP[5];                               \
    float t3_ = m[6] * KP[6] + m[7] * KP[7];                               \
    float p_ = (t0_ + t1_) + (t2_ + t3_);                                  \
    p_ = redu16(p_);                                                       \
    float s_ = PR - p_;                                                    \
    m[0] += s_ * KP[0]; m[1] += s_ * KP[1]; m[2] += s_ * KP[2];            \
    m[3] += s_ * KP[3]; m[4] += s_ * KP[4]; m[5] += s_ * KP[5];            \
    m[6] += s_ * KP[6]; m[7] += s_ * KP[7];                                \
  } while (0)

__global__ __launch_bounds__(256, 1) void scan_kernel(const float* __restrict__ khat,
                                                      const float* __restrict__ kT,
                                                      float* __restrict__ c) {
  int bid = blockIdx.x;
  int idxm = bid & 31;  // 8 blocks of one idxm land on one XCD (round-robin dispatch)
  int rg = bid >> 5;
  int b = idxm >> 1, mat = idxm & 1;
  const float* kh = khat + (size_t)idxm * L_ * HALF_;
  const float* kTi = kT + (size_t)idxm * HALF_ * L_;

  int tid = threadIdx.x;
  int seg = tid & 15;
  int rl = tid >> 4;
  int r = rg * 16 + rl;
  int c0 = seg * 8;
  const float* krow = kTi + (size_t)r * L_;  // raw k_t[r], t-contiguous

  float m[8];
#pragma unroll
  for (int g = 0; g < 8; g++) m[g] = 0.f;

  float pk[8][8];
  float kr[8];
#pragma unroll
  for (int u = 0; u < 8; u++) {
    *(float4*)&pk[u][0] = *(const float4*)(kh + (size_t)u * HALF_ + c0);
    *(float4*)&pk[u][4] = *(const float4*)(kh + (size_t)u * HALF_ + c0 + 4);
  }
  *(float4*)&kr[0] = *(const float4*)(krow);
  *(float4*)&kr[4] = *(const float4*)(krow + 4);

  // steps 0..503 in 63 blocks of 8; prefetch next 8 spread across the block
  for (int i = 0; i < 63; i++) {
    int nt = (i + 1) * 8;
    const float* knext = kh + (size_t)nt * HALF_ + c0;
#pragma unroll
    for (int u = 0; u < 8; u++) {
      STEP8(pk[u], kr[u]);
      *(float4*)&pk[u][0] = *(const float4*)(knext + (size_t)u * HALF_);
      *(float4*)&pk[u][4] = *(const float4*)(knext + (size_t)u * HALF_ + 4);
      if (u == 3) *(float4*)&kr[0] = *(const float4*)(krow + nt);
      if (u == 7) *(float4*)&kr[4] = *(const float4*)(krow + nt + 4);
    }
  }
  // tail: steps 504..510 (7 steps); pk[u]=step 504+u
#pragma unroll
  for (int u = 0; u < 7; u++) STEP8(pk[u], kr[u]);

  // final read with raw last-token key (t=511), gathered from kT columns
  float q[8];
#pragma unroll
  for (int j = 0; j < 8; j++) q[j] = kTi[(size_t)(c0 + j) * L_ + 511];
  float t0 = m[0] * q[0] + m[1] * q[1];
  float t1 = m[2] * q[2] + m[3] * q[3];
  float t2 = m[4] * q[4] + m[5] * q[5];
  float t3 = m[6] * q[6] + m[7] * q[7];
  float p = redu16((t0 + t1) + (t2 + t3));
  if (seg == 0) c[(size_t)b * H_ + mat * HALF_ + r] = p;
}

// ---------------- r = c @ W_rp^T + b_rp ----------------
__global__ void rp_kernel(const float* __restrict__ c, const float* __restrict__ Wrp,
                          const float* __restrict__ brp, float* __restrict__ r) {
  int b = blockIdx.x;
  int n = threadIdx.x;  // 256
  __shared__ float cs[H_];
  cs[n] = c[(size_t)b * H_ + n];
  __syncthreads();
  const float4* w4 = (const float4*)(Wrp + (size_t)n * H_);
  const float4* c4 = (const float4*)cs;
  float acc = 0.f;
#pragma unroll 8
  for (int k = 0; k < H_ / 4; k++) {
    float4 w = w4[k], cc = c4[k];
    acc += w.x * cc.x + w.y * cc.y + w.z * cc.z + w.w * cc.w;
  }
  r[(size_t)b * H_ + n] = acc + brp[n];
}

// ---------------- out = r @ W_out^T + b_out, coalesced: 64 vocab rows/block ----------------
__global__ __launch_bounds__(256) void out_kernel(const float* __restrict__ r,
                                                  const float* __restrict__ Wout,
                                                  const float* __restrict__ bout,
                                                  float* __restrict__ out) {
  __shared__ float rs[16 * 272];
  __shared__ float obuf[16 * 68];
  int tid = threadIdx.x;
#pragma unroll
  for (int q = 0; q < 16; q++) {
    int idx = q * 256 + tid;
    int bb = idx >> 8, cc = idx & 255;
    rs[bb * 272 + cc + 4 * (cc >> 6)] = r[idx];
  }
  __syncthreads();
  int row = tid >> 2, part = tid & 3;
  int v = blockIdx.x * 64 + row;
  const float4* w4 = (const float4*)(Wout + (size_t)v * H_ + part * 64);
  float acc[16];
#pragma unroll
  for (int bb = 0; bb < 16; bb++) acc[bb] = 0.f;
#pragma unroll 4
  for (int j = 0; j < 16; j++) {
    float4 w = w4[j];
#pragma unroll
    for (int bb = 0; bb < 16; bb++) {
      float4 rv = *(const float4*)&rs[bb * 272 + part * 68 + j * 4];
      acc[bb] += w.x * rv.x + w.y * rv.y + w.z * rv.z + w.w * rv.w;
    }
  }
  float bo = bout[v];
#pragma unroll
  for (int bb = 0; bb < 16; bb++) {
    acc[bb] = dpp_xor_add<0xB1>(acc[bb]);
    acc[bb] = dpp_xor_add<0x4E>(acc[bb]);
  }
#pragma unroll
  for (int q = 0; q < 4; q++) {
    int bb = part * 4 + q;
    obuf[bb * 68 + row] = acc[bb] + bo;
  }
  __syncthreads();
#pragma unroll
  for (int q = 0; q < 4; q++) {
    int idx = q * 256 + tid;
    int bb = idx >> 6, vl = idx & 63;
    out[(size_t)bb * V_ + blockIdx.x * 64 + vl] = obuf[bb * 68 + vl];
  }
}

extern "C" void kernel_launch(void* const* d_in, const int* in_sizes, int n_in,
                              void* d_out, int out_size, void* d_ws, size_t ws_size,
                              hipStream_t stream) {
  const int* seq = (const int*)d_in[0];
  const float* embed = (const float*)d_in[1];
  const float* W1 = (const float*)d_in[2];
  const float* b1 = (const float*)d_in[3];
  const float* W2 = (const float*)d_in[4];
  const float* b2 = (const float*)d_in[5];
  const float* gamma = (const float*)d_in[6];
  const float* beta = (const float*)d_in[7];
  const float* Wsem = (const float*)d_in[8];
  const float* Wepi = (const float*)d_in[9];
  const float* Wrp = (const float*)d_in[10];
  const float* brp = (const float*)d_in[11];
  const float* Wout = (const float*)d_in[12];
  const float* bout = (const float*)d_in[13];
  float* out = (float*)d_out;

  float* ws = (float*)d_ws;
  unsigned short* a1b = (unsigned short*)ws;               // [8192,512] bf16 -> 2,097,152 fl
  unsigned short* hnb = (unsigned short*)(ws + 2097152);   // [8192,256] bf16 -> 1,048,576 fl
  float* khat = ws + 3145728;                              // [32,512,128] fp32
  float* kT = ws + 5242880;                                // [32,128,512] fp32
  unsigned short* W1b = (unsigned short*)(ws + 7340032);   // 131072 bf16
  unsigned short* W2b = (unsigned short*)(ws + 7405568);   // 131072 bf16
  unsigned short* Wcb = (unsigned short*)(ws + 7471104);   // 65536 bf16
  float* c = ws + 7503872;                                 // [16,256]
  float* r = ws + 7507968;                                 // [16,256]

  // 1. weights -> bf16
  wconv_kernel<<<1280, 256, 0, stream>>>(W1, W2, Wsem, Wepi, W1b, W2b, Wcb);
  // 2. a1 = relu(embed[seq] @ W1^T + b1) -> bf16 (gather fused)
  gemm1_kernel<<<dim3(4, 64), 256, 0, stream>>>(seq, embed, W1b, b1, a1b);
  // 3. hn = LN(a1 @ W2^T + b2 + embed[seq]) -> bf16 (residual gather + LN fused)
  mlp2_kernel<<<256, 256, 0, stream>>>(a1b, W2b, b2, seq, embed, gamma, beta, hnb);
  // 4. k-projection + normalize + transpose (khat fp32, kT raw fp32)
  kproj_kernel<<<256, 256, 0, stream>>>(hnb, Wcb, khat, kT);
  // 5. delta-rule scan -> c [16,256]
  scan_kernel<<<256, 256, 0, stream>>>(khat, kT, c);
  // 6. r = c @ Wrp^T + brp
  rp_kernel<<<16, 256, 0, stream>>>(c, Wrp, brp, r);
  // 7. out = r @ Wout^T + bout  [16,32000]
  out_kernel<<<500, 256, 0, stream>>>(r, Wout, bout, out);
}

// Round 7
// 231.372 us; speedup vs baseline: 1.1742x; 1.0671x over previous
//
#include <hip/hip_runtime.h>

#define B_ 16
#define L_ 512
#define H_ 256
#define V_ 32000
#define HALF_ 128

typedef __attribute__((ext_vector_type(8))) short short8;
typedef __attribute__((ext_vector_type(4))) float floatx4;

__device__ __forceinline__ unsigned short f2bf(float x) {
  unsigned int u = __float_as_uint(x);
  unsigned int r = (u + 0x7FFFu + ((u >> 16) & 1u)) >> 16;
  return (unsigned short)r;
}

template <int CTRL>
__device__ __forceinline__ float dpp_xor_add(float x) {
  int y = __builtin_amdgcn_mov_dpp(__float_as_int(x), CTRL, 0xf, 0xf, true);
  return x + __int_as_float(y);
}

// butterfly sum over aligned 16-lane groups; ALL lanes get the result
__device__ __forceinline__ float redu16(float p) {
  p = dpp_xor_add<0xB1>(p);   // xor1
  p = dpp_xor_add<0x4E>(p);   // xor2
  p = dpp_xor_add<0x141>(p);  // row_half_mirror
  p = dpp_xor_add<0x140>(p);  // row_mirror
  return p;
}

// async global->LDS copy, 16B per lane, wave-uniform LDS base
__device__ __forceinline__ void async_cp16(const float* g, float* l) {
  __builtin_amdgcn_global_load_lds(
      (const __attribute__((address_space(1))) void*)g,
      (__attribute__((address_space(3))) void*)l, 16, 0, 0);
}

// ---------------- prep: embedding gather (fp32+bf16) + weight bf16 conversion ----------------
__global__ __launch_bounds__(256) void prep_kernel(const int* __restrict__ seq,
                                                   const float* __restrict__ embed,
                                                   float* __restrict__ h,
                                                   unsigned short* __restrict__ hbf,
                                                   const float* __restrict__ W1,
                                                   const float* __restrict__ W2,
                                                   const float* __restrict__ Ws,
                                                   const float* __restrict__ We,
                                                   unsigned short* __restrict__ W1b,
                                                   unsigned short* __restrict__ W2b,
                                                   unsigned short* __restrict__ Wcb) {
  int blk = blockIdx.x;
  int tid = threadIdx.x;
  if (blk < 2048) {
    int token = blk * 4 + (tid >> 6);
    int lane = tid & 63;
    int row = seq[token];
    float4 v = ((const float4*)(embed + (size_t)row * H_))[lane];
    ((float4*)(h + (size_t)token * H_))[lane] = v;
    ushort4 o;
    o.x = f2bf(v.x); o.y = f2bf(v.y); o.z = f2bf(v.z); o.w = f2bf(v.w);
    *(ushort4*)(hbf + (size_t)token * H_ + lane * 4) = o;
  } else {
    int i = (blk - 2048) * 256 + tid;  // 0..327679
    if (i < 131072) W1b[i] = f2bf(W1[i]);
    else if (i < 262144) W2b[i - 131072] = f2bf(W2[i - 131072]);
    else if (i < 294912) Wcb[i - 262144] = f2bf(Ws[i - 262144]);
    else Wcb[i - 262144] = f2bf(We[i - 294912]);
  }
}

// ---------------- bf16 MFMA GEMM with global prefetch: C = act(A @ B^T + bias + Res) ----------------
template <int MT, bool RELU, bool BIAS, bool RES, bool OUT_BF16>
__global__ __launch_bounds__(256) void gemm_mfma(const unsigned short* __restrict__ A,
                                                 const unsigned short* __restrict__ Bw,
                                                 const float* __restrict__ bias,
                                                 const float* __restrict__ Res,
                                                 float* __restrict__ Cf,
                                                 unsigned short* __restrict__ Cb,
                                                 int M, int N, int K) {
  constexpr int FI = MT / 32;
  __shared__ unsigned short As[MT * 40];
  __shared__ unsigned short Bs[128 * 40];
  int tid = threadIdx.x;
  int wave = tid >> 6, lane = tid & 63;
  int wm = (wave >> 1) * (MT / 2), wn = (wave & 1) * 64;
  int quad = lane >> 4, l15 = lane & 15;
  int bm = blockIdx.y * MT, bn = blockIdx.x * 128;
  int sr = tid >> 2, sq = tid & 3;

  floatx4 zero = {0.f, 0.f, 0.f, 0.f};
  floatx4 acc[FI][4];
#pragma unroll
  for (int fi = 0; fi < FI; fi++)
#pragma unroll
    for (int fj = 0; fj < 4; fj++) acc[fi][fj] = zero;

  // prefetch chunk 0
  uint4 av0, av1, bv0, bv1;
  av0 = *(const uint4*)(A + (size_t)(bm + sr) * K + sq * 8);
  if (MT == 128) av1 = *(const uint4*)(A + (size_t)(bm + 64 + sr) * K + sq * 8);
  bv0 = *(const uint4*)(Bw + (size_t)(bn + sr) * K + sq * 8);
  bv1 = *(const uint4*)(Bw + (size_t)(bn + 64 + sr) * K + sq * 8);

  for (int k0 = 0; k0 < K; k0 += 32) {
    __syncthreads();
    *(uint4*)(As + sr * 40 + sq * 8) = av0;
    if (MT == 128) *(uint4*)(As + (64 + sr) * 40 + sq * 8) = av1;
    *(uint4*)(Bs + sr * 40 + sq * 8) = bv0;
    *(uint4*)(Bs + (64 + sr) * 40 + sq * 8) = bv1;
    __syncthreads();
    if (k0 + 32 < K) {  // prefetch next chunk while MFMAs run
      av0 = *(const uint4*)(A + (size_t)(bm + sr) * K + k0 + 32 + sq * 8);
      if (MT == 128) av1 = *(const uint4*)(A + (size_t)(bm + 64 + sr) * K + k0 + 32 + sq * 8);
      bv0 = *(const uint4*)(Bw + (size_t)(bn + sr) * K + k0 + 32 + sq * 8);
      bv1 = *(const uint4*)(Bw + (size_t)(bn + 64 + sr) * K + k0 + 32 + sq * 8);
    }
    short8 af[FI], bf[4];
#pragma unroll
    for (int f = 0; f < FI; f++) af[f] = *(const short8*)(As + (wm + f * 16 + l15) * 40 + quad * 8);
#pragma unroll
    for (int f = 0; f < 4; f++) bf[f] = *(const short8*)(Bs + (wn + f * 16 + l15) * 40 + quad * 8);
#pragma unroll
    for (int fi = 0; fi < FI; fi++)
#pragma unroll
      for (int fj = 0; fj < 4; fj++)
        acc[fi][fj] = __builtin_amdgcn_mfma_f32_16x16x32_bf16(af[fi], bf[fj], acc[fi][fj], 0, 0, 0);
  }

#pragma unroll
  for (int fi = 0; fi < FI; fi++) {
#pragma unroll
    for (int fj = 0; fj < 4; fj++) {
      int col = bn + wn + fj * 16 + l15;
      float bb = BIAS ? bias[col] : 0.f;
#pragma unroll
      for (int rg = 0; rg < 4; rg++) {
        int row = bm + wm + fi * 16 + quad * 4 + rg;
        float v = acc[fi][fj][rg] + bb;
        if (RES) v += Res[(size_t)row * N + col];
        if (RELU) v = fmaxf(v, 0.f);
        if (OUT_BF16) Cb[(size_t)row * N + col] = f2bf(v);
        else Cf[(size_t)row * N + col] = v;
      }
    }
  }
}

// ---------------- LayerNorm over H=256, one wave per row; bf16 output ----------------
__global__ void ln_kernel(const float* __restrict__ x, const float* __restrict__ gamma,
                          const float* __restrict__ beta, unsigned short* __restrict__ yb) {
  int row = blockIdx.x;
  int lane = threadIdx.x;  // 64
  float4 v = ((const float4*)(x + (size_t)row * H_))[lane];
  float s = v.x + v.y + v.z + v.w;
  float sq = v.x * v.x + v.y * v.y + v.z * v.z + v.w * v.w;
#pragma unroll
  for (int off = 32; off >= 1; off >>= 1) {
    s += __shfl_xor(s, off);
    sq += __shfl_xor(sq, off);
  }
  float mu = s * (1.f / H_);
  float var = sq * (1.f / H_) - mu * mu;
  float inv = rsqrtf(var + 1e-5f);
  float4 g = ((const float4*)gamma)[lane];
  float4 b = ((const float4*)beta)[lane];
  ushort4 o;
  o.x = f2bf((v.x - mu) * inv * g.x + b.x);
  o.y = f2bf((v.y - mu) * inv * g.y + b.y);
  o.z = f2bf((v.z - mu) * inv * g.z + b.z);
  o.w = f2bf((v.w - mu) * inv * g.w + b.w);
  *(ushort4*)(yb + (size_t)row * H_ + lane * 4) = o;
}

// ---------------- KPROJ: k = hn @ [Wsem;Wepi]^T; khat fp32 (granule-permuted) + raw kT ----------------
// 32x256 tile; each wave owns a full 128-dim half -> pure-DPP norms. Global prefetch in K-loop.
__global__ __launch_bounds__(256) void kproj_kernel(const unsigned short* __restrict__ hnb,
                                                    const unsigned short* __restrict__ Wcb,
                                                    float* __restrict__ khat,
                                                    float* __restrict__ kT) {
  __shared__ unsigned short As[32 * 40];
  __shared__ unsigned short Bs[256 * 40];
  int tid = threadIdx.x;
  int wave = tid >> 6, lane = tid & 63;
  int wm = (wave >> 1) * 16, wnh = wave & 1, wn = wnh * 128;
  int quad = lane >> 4, l15 = lane & 15;
  int bm = blockIdx.x * 32;

  floatx4 zero = {0.f, 0.f, 0.f, 0.f};
  floatx4 acc[8];
#pragma unroll
  for (int fj = 0; fj < 8; fj++) acc[fj] = zero;

  int sr = tid >> 2, sq = tid & 3;
  uint4 av, bv[4];
  if (tid < 128) av = *(const uint4*)(hnb + (size_t)(bm + sr) * H_ + sq * 8);
#pragma unroll
  for (int q = 0; q < 4; q++) {
    int unit = q * 256 + tid;
    bv[q] = *(const uint4*)(Wcb + (size_t)(unit >> 2) * H_ + (unit & 3) * 8);
  }

  for (int k0 = 0; k0 < 256; k0 += 32) {
    __syncthreads();
    if (tid < 128) *(uint4*)(As + sr * 40 + sq * 8) = av;
#pragma unroll
    for (int q = 0; q < 4; q++) {
      int unit = q * 256 + tid;
      *(uint4*)(Bs + (unit >> 2) * 40 + (unit & 3) * 8) = bv[q];
    }
    __syncthreads();
    if (k0 + 32 < 256) {
      if (tid < 128) av = *(const uint4*)(hnb + (size_t)(bm + sr) * H_ + k0 + 32 + sq * 8);
#pragma unroll
      for (int q = 0; q < 4; q++) {
        int unit = q * 256 + tid;
        bv[q] = *(const uint4*)(Wcb + (size_t)(unit >> 2) * H_ + k0 + 32 + (unit & 3) * 8);
      }
    }
    short8 af = *(const short8*)(As + (wm + l15) * 40 + quad * 8);
    short8 bf[8];
#pragma unroll
    for (int fj = 0; fj < 8; fj++)
      bf[fj] = *(const short8*)(Bs + (wn + fj * 16 + l15) * 40 + quad * 8);
#pragma unroll
    for (int fj = 0; fj < 8; fj++)
      acc[fj] = __builtin_amdgcn_mfma_f32_16x16x32_bf16(af, bf[fj], acc[fj], 0, 0, 0);
  }

  // epilogue: per-row L2 norm over this wave's 128-col half
  int b = bm >> 9;
  int idxm = b * 2 + wnh;
  int tloc0 = (bm & 511) + wm + quad * 4;
  float inv[4];
#pragma unroll
  for (int rg = 0; rg < 4; rg++) {
    float ssq = 0.f;
#pragma unroll
    for (int fj = 0; fj < 8; fj++) ssq += acc[fj][rg] * acc[fj][rg];
    ssq = redu16(ssq);
    inv[rg] = 1.f / fmaxf(sqrtf(ssq), 1e-12f);
  }
#pragma unroll
  for (int fj = 0; fj < 8; fj++) {
    int ch = fj * 16 + l15;             // logical col 0..127
    int j = ch >> 2, e = ch & 3;        // float4 granule + elem
    int pj = (j & 1) ? (16 + (j >> 1)) : (j >> 1);  // even granules first
    int pcol = pj * 4 + e;
#pragma unroll
    for (int rg = 0; rg < 4; rg++)
      khat[((size_t)idxm * L_ + tloc0 + rg) * HALF_ + pcol] = acc[fj][rg] * inv[rg];
    float4 raw = {acc[fj][0], acc[fj][1], acc[fj][2], acc[fj][3]};
    *(float4*)(kT + (size_t)idxm * (HALF_ * L_) + (size_t)ch * L_ + tloc0) = raw;
  }
}

// ---------------- scan: LDS-staged khat (async), 4-deep ds_read ring ----------------
#define STEP(KP, KR)                                                     \
  do {                                                                   \
    float t0_ = m[0] * KP[0] + m[1] * KP[1];                             \
    float t1_ = m[2] * KP[2] + m[3] * KP[3];                             \
    float t2_ = m[4] * KP[4] + m[5] * KP[5];                             \
    float t3_ = m[6] * KP[6] + m[7] * KP[7];                             \
    float p_ = (t0_ + t1_) + (t2_ + t3_);                                \
    p_ = redu16(p_);                                                     \
    float s_ = (KR) - p_;                                                \
    m[0] += s_ * KP[0]; m[1] += s_ * KP[1]; m[2] += s_ * KP[2];          \
    m[3] += s_ * KP[3]; m[4] += s_ * KP[4]; m[5] += s_ * KP[5];          \
    m[6] += s_ * KP[6]; m[7] += s_ * KP[7];                              \
  } while (0)

__global__ __launch_bounds__(256) void scan_kernel(const float* __restrict__ khat,
                                                   const float* __restrict__ kT,
                                                   float* __restrict__ c) {
  __shared__ float sk[2][64 * 128];  // 2 x 32 KB double buffer
  int bid = blockIdx.x;
  int idxm = bid & 31;
  int rg = bid >> 5;
  int b = idxm >> 1, mat = idxm & 1;
  const float* kh = khat + (size_t)idxm * L_ * HALF_;
  const float* kTi = kT + (size_t)idxm * HALF_ * L_;

  int tid = threadIdx.x;
  int wave = tid >> 6, lane = tid & 63;
  int seg = tid & 15, rl = tid >> 4;
  int r = rg * 16 + rl;
  int c0 = seg * 8;
  const float* krow = kTi + (size_t)r * L_;

  float m[8];
#pragma unroll
  for (int g = 0; g < 8; g++) m[g] = 0.f;

  // stage chunk 0 into buf 0
  {
    const float* g0 = kh + wave * 2048 + lane * 4;
    float* l0 = &sk[0][wave * 2048];
#pragma unroll
    for (int j = 0; j < 8; j++) async_cp16(g0 + j * 256, l0 + j * 256);
  }
  __syncthreads();

  float4 krn = *(const float4*)(krow);  // raw keys, steps 0..3
  const float* lb = &sk[0][0] + seg * 4;

  // chunks 0..6 (full 64 steps each)
  for (int ch = 0; ch < 7; ch++) {
    {  // stage chunk ch+1 into the other buffer (async, drains at end-of-chunk barrier)
      const float* gs = kh + (size_t)(ch + 1) * 8192 + wave * 2048 + lane * 4;
      float* ls = &sk[(ch + 1) & 1][wave * 2048];
#pragma unroll
      for (int j = 0; j < 8; j++) async_cp16(gs + j * 256, ls + j * 256);
    }
    const float* base = lb + (ch & 1) * 8192;
    float pk[4][8];
#pragma unroll
    for (int u = 0; u < 4; u++) {
      *(float4*)&pk[u][0] = *(const float4*)(base + u * 128);
      *(float4*)&pk[u][4] = *(const float4*)(base + u * 128 + 64);
    }
    for (int g = 0; g < 15; g++) {
      float4 krc = krn;
      krn = *(const float4*)(krow + ch * 64 + g * 4 + 4);
#pragma unroll
      for (int u = 0; u < 4; u++) {
        STEP(pk[u], ((u == 0) ? krc.x : (u == 1) ? krc.y : (u == 2) ? krc.z : krc.w));
        int tn = g * 4 + u + 4;
        *(float4*)&pk[u][0] = *(const float4*)(base + tn * 128);
        *(float4*)&pk[u][4] = *(const float4*)(base + tn * 128 + 64);
      }
    }
    {  // last 4 steps of chunk, no prefetch
      float4 krc = krn;
      krn = *(const float4*)(krow + ch * 64 + 64);
      STEP(pk[0], krc.x);
      STEP(pk[1], krc.y);
      STEP(pk[2], krc.z);
      STEP(pk[3], krc.w);
    }
    __syncthreads();
  }

  // chunk 7: steps 448..510 (63 updates)
  {
    const float* base = lb + 8192;  // buf 1
    float pk[4][8];
#pragma unroll
    for (int u = 0; u < 4; u++) {
      *(float4*)&pk[u][0] = *(const float4*)(base + u * 128);
      *(float4*)&pk[u][4] = *(const float4*)(base + u * 128 + 64);
    }
    for (int g = 0; g < 15; g++) {
      float4 krc = krn;
      krn = *(const float4*)(krow + 448 + g * 4 + 4);
#pragma unroll
      for (int u = 0; u < 4; u++) {
        STEP(pk[u], ((u == 0) ? krc.x : (u == 1) ? krc.y : (u == 2) ? krc.z : krc.w));
        int tn = g * 4 + u + 4;
        *(float4*)&pk[u][0] = *(const float4*)(base + tn * 128);
        *(float4*)&pk[u][4] = *(const float4*)(base + tn * 128 + 64);
      }
    }
    float4 krc = krn;  // raw keys for steps 508..511
    STEP(pk[0], krc.x);  // 508
    STEP(pk[1], krc.y);  // 509
    STEP(pk[2], krc.z);  // 510
  }

  // final read with raw last-token key (t=511), gathered from kT columns
  float q[8];
#pragma unroll
  for (int j = 0; j < 8; j++) q[j] = kTi[(size_t)(c0 + j) * L_ + 511];
  float t0 = m[0] * q[0] + m[1] * q[1];
  float t1 = m[2] * q[2] + m[3] * q[3];
  float t2 = m[4] * q[4] + m[5] * q[5];
  float t3 = m[6] * q[6] + m[7] * q[7];
  float p = redu16((t0 + t1) + (t2 + t3));
  if (seg == 0) c[(size_t)b * H_ + mat * HALF_ + r] = p;
}

// ---------------- r = c @ W_rp^T + b_rp ----------------
__global__ void rp_kernel(const float* __restrict__ c, const float* __restrict__ Wrp,
                          const float* __restrict__ brp, float* __restrict__ r) {
  int b = blockIdx.x;
  int n = threadIdx.x;  // 256
  __shared__ float cs[H_];
  cs[n] = c[(size_t)b * H_ + n];
  __syncthreads();
  const float4* w4 = (const float4*)(Wrp + (size_t)n * H_);
  const float4* c4 = (const float4*)cs;
  float acc = 0.f;
#pragma unroll 8
  for (int k = 0; k < H_ / 4; k++) {
    float4 w = w4[k], cc = c4[k];
    acc += w.x * cc.x + w.y * cc.y + w.z * cc.z + w.w * cc.w;
  }
  r[(size_t)b * H_ + n] = acc + brp[n];
}

// ---------------- out = r @ W_out^T + b_out, coalesced ----------------
__global__ __launch_bounds__(256) void out_kernel(const float* __restrict__ r,
                                                  const float* __restrict__ Wout,
                                                  const float* __restrict__ bout,
                                                  float* __restrict__ out) {
  __shared__ float rs[16 * 272];
  __shared__ float obuf[16 * 68];
  int tid = threadIdx.x;
#pragma unroll
  for (int q = 0; q < 16; q++) {
    int idx = q * 256 + tid;
    int bb = idx >> 8, cc = idx & 255;
    rs[bb * 272 + cc + 4 * (cc >> 6)] = r[idx];
  }
  __syncthreads();
  int row = tid >> 2, part = tid & 3;
  int v = blockIdx.x * 64 + row;
  const float4* w4 = (const float4*)(Wout + (size_t)v * H_ + part * 64);
  float acc[16];
#pragma unroll
  for (int bb = 0; bb < 16; bb++) acc[bb] = 0.f;
#pragma unroll 4
  for (int j = 0; j < 16; j++) {
    float4 w = w4[j];
#pragma unroll
    for (int bb = 0; bb < 16; bb++) {
      float4 rv = *(const float4*)&rs[bb * 272 + part * 68 + j * 4];
      acc[bb] += w.x * rv.x + w.y * rv.y + w.z * rv.z + w.w * rv.w;
    }
  }
  float bo = bout[v];
#pragma unroll
  for (int bb = 0; bb < 16; bb++) {
    acc[bb] = dpp_xor_add<0xB1>(acc[bb]);
    acc[bb] = dpp_xor_add<0x4E>(acc[bb]);
  }
#pragma unroll
  for (int q = 0; q < 4; q++) {
    int bb = part * 4 + q;
    obuf[bb * 68 + row] = acc[bb] + bo;
  }
  __syncthreads();
#pragma unroll
  for (int q = 0; q < 4; q++) {
    int idx = q * 256 + tid;
    int bb = idx >> 6, vl = idx & 63;
    out[(size_t)bb * V_ + blockIdx.x * 64 + vl] = obuf[bb * 68 + vl];
  }
}

extern "C" void kernel_launch(void* const* d_in, const int* in_sizes, int n_in,
                              void* d_out, int out_size, void* d_ws, size_t ws_size,
                              hipStream_t stream) {
  const int* seq = (const int*)d_in[0];
  const float* embed = (const float*)d_in[1];
  const float* W1 = (const float*)d_in[2];
  const float* b1 = (const float*)d_in[3];
  const float* W2 = (const float*)d_in[4];
  const float* b2 = (const float*)d_in[5];
  const float* gamma = (const float*)d_in[6];
  const float* beta = (const float*)d_in[7];
  const float* Wsem = (const float*)d_in[8];
  const float* Wepi = (const float*)d_in[9];
  const float* Wrp = (const float*)d_in[10];
  const float* brp = (const float*)d_in[11];
  const float* Wout = (const float*)d_in[12];
  const float* bout = (const float*)d_in[13];
  float* out = (float*)d_out;

  // Workspace layout (float-slot offsets), NO overlapping live ranges:
  //  [0        , 2097152 )  h fp32 (x in-place)  -> later kT (h dead after ln)
  //  [2097152  , 4194304 )  a1b bf16 [8192,512]  -> later khat (a1b dead after gemm2)
  //  [4194304  , 5242880 )  hbf bf16 [8192,256]
  //  [5242880  , 6291456 )  hnb bf16 [8192,256]
  //  [6291456  , 6356992 )  W1b bf16 131072
  //  [6356992  , 6422528 )  W2b bf16 131072
  //  [6422528  , 6455296 )  Wcb bf16 65536
  //  [6455296  , 6459392 )  c  [16,256]
  //  [6459392  , 6463488 )  r  [16,256]
  float* ws = (float*)d_ws;
  float* h = ws;
  float* kT = ws;
  unsigned short* a1b = (unsigned short*)(ws + 2097152);
  float* khat = ws + 2097152;
  unsigned short* hbf = (unsigned short*)(ws + 4194304);
  unsigned short* hnb = (unsigned short*)(ws + 5242880);
  unsigned short* W1b = (unsigned short*)(ws + 6291456);
  unsigned short* W2b = (unsigned short*)(ws + 6356992);
  unsigned short* Wcb = (unsigned short*)(ws + 6422528);
  float* c = ws + 6455296;
  float* r = ws + 6459392;

  // 1. gather (h fp32 + hbf bf16) + weight conversion
  prep_kernel<<<3328, 256, 0, stream>>>(seq, embed, h, hbf, W1, W2, Wsem, Wepi, W1b, W2b, Wcb);
  // 2. a1 = relu(h @ W1^T + b1) -> bf16
  gemm_mfma<128, true, true, false, true><<<dim3(4, 64), 256, 0, stream>>>(
      hbf, W1b, b1, nullptr, nullptr, a1b, 8192, 512, 256);
  // 3. x = a1 @ W2^T + b2 + h -> fp32 in-place over h
  gemm_mfma<64, false, true, true, false><<<dim3(2, 128), 256, 0, stream>>>(
      a1b, W2b, b2, h, h, nullptr, 8192, 256, 512);
  // 4. hn = LayerNorm(x) -> bf16
  ln_kernel<<<8192, 64, 0, stream>>>(h, gamma, beta, hnb);
  // 5. k-projection + normalize + permute/transpose (khat over a1b, kT over h)
  kproj_kernel<<<256, 256, 0, stream>>>(hnb, Wcb, khat, kT);
  // 6. delta-rule scan -> c [16,256]
  scan_kernel<<<256, 256, 0, stream>>>(khat, kT, c);
  // 7. r = c @ Wrp^T + brp
  rp_kernel<<<16, 256, 0, stream>>>(c, Wrp, brp, r);
  // 8. out = r @ Wout^T + bout
  out_kernel<<<500, 256, 0, stream>>>(r, Wout, bout, out);
}